// Round 12
// baseline (123.967 us; speedup 1.0000x reference)
//
#include <hip/hip_runtime.h>

typedef __bf16 bf16x8 __attribute__((ext_vector_type(8)));
typedef float f32x4 __attribute__((ext_vector_type(4)));
typedef float f32x16 __attribute__((ext_vector_type(16)));
typedef unsigned short u16x8 __attribute__((ext_vector_type(8)));
typedef unsigned int u32x4 __attribute__((ext_vector_type(4)));
typedef int i32x2 __attribute__((ext_vector_type(2)));

__device__ inline unsigned short f2bf(float f) {
    __bf16 h = (__bf16)f;
    return __builtin_bit_cast(unsigned short, h);
}

__device__ inline unsigned int pkbf(float lo, float hi) {
    return (unsigned int)f2bf(lo) | ((unsigned int)f2bf(hi) << 16);
}

__device__ inline float fexp2(float x) {
#if __has_builtin(__builtin_amdgcn_exp2f)
    return __builtin_amdgcn_exp2f(x);
#else
    return exp2f(x);
#endif
}

__device__ inline f32x4 mfma16(u16x8 a, u16x8 b, f32x4 c) {
    return __builtin_amdgcn_mfma_f32_16x16x32_bf16(
        __builtin_bit_cast(bf16x8, a), __builtin_bit_cast(bf16x8, b), c, 0, 0, 0);
}

__device__ inline f32x16 mfma32(u16x8 a, u16x8 b, f32x16 c) {
    return __builtin_amdgcn_mfma_f32_32x32x16_bf16(
        __builtin_bit_cast(bf16x8, a), __builtin_bit_cast(bf16x8, b), c, 0, 0, 0);
}

__device__ inline i32x2 permswap(unsigned int a, unsigned int b, int hi) {
#if __has_builtin(__builtin_amdgcn_permlane32_swap)
    (void)hi;
    return __builtin_amdgcn_permlane32_swap((int)a, (int)b, false, false);
#else
    int pa_ = __shfl_xor((int)a, 32);
    int pb_ = __shfl_xor((int)b, 32);
    i32x2 r;
    r[0] = hi ? pb_ : (int)a;
    r[1] = hi ? (int)b : pa_;
    return r;
#endif
}

__device__ inline void gld_lds16(const unsigned short* gsrc, unsigned short* ldst) {
    __builtin_amdgcn_global_load_lds(
        (const __attribute__((address_space(1))) unsigned int*)gsrc,
        (__attribute__((address_space(3))) unsigned int*)ldst, 16, 0, 0);
}

#define WAIT_VM(n)                                          \
    asm volatile("s_waitcnt vmcnt(" #n ")" ::: "memory");   \
    __builtin_amdgcn_sched_barrier(0)
#define WAIT_LGKM0                                          \
    asm volatile("s_waitcnt lgkmcnt(0)" ::: "memory");      \
    __builtin_amdgcn_sched_barrier(0)
#define BARRIER                                             \
    __builtin_amdgcn_s_barrier();                           \
    __builtin_amdgcn_sched_barrier(0)

// ---------------- elementwise f32 -> bf16 ----------------
__global__ __launch_bounds__(256) void cvt_f32_bf16(const float* __restrict__ in,
                                                    unsigned short* __restrict__ out, long n) {
    long i = ((long)blockIdx.x * blockDim.x + threadIdx.x) * 4;
    if (i >= n) return;
    float4 v = *(const float4*)(in + i);
    ushort4 r;
    r.x = f2bf(v.x); r.y = f2bf(v.y); r.z = f2bf(v.z); r.w = f2bf(v.w);
    *(ushort4*)(out + i) = r;
}

// ---------------- tiled transpose: W (K,N) f32 -> Wt (N,K) bf16, * scale ----------------
__global__ __launch_bounds__(256) void transpose_cvt_tiled(const float* __restrict__ W,
                                                           unsigned short* __restrict__ Wt,
                                                           int K, int N, float scale) {
    __shared__ float tile[64][65];
    const int n0 = blockIdx.x * 64, k0 = blockIdx.y * 64;
    const int c = threadIdx.x & 63;
    const int r4 = threadIdx.x >> 6;
#pragma unroll
    for (int i = 0; i < 16; i++) {
        int r = r4 * 16 + i;
        tile[r][c] = W[(long)(k0 + r) * N + n0 + c];
    }
    __syncthreads();
#pragma unroll
    for (int i = 0; i < 16; i++) {
        int rr = r4 * 16 + i;
        Wt[(long)(n0 + rr) * K + k0 + c] = f2bf(tile[c][rr] * scale);
    }
}

// ---------------- GEMM: C[m][n] = sum_k A[m][k] * Bt[n][k] ----------------
// 128x128 tile, BK=32, 4 waves, dbuf LDS, counted-vmcnt 2-barrier pipeline.
template<int WRITE_BF16, int MASKED>
__global__ __launch_bounds__(256) void gemm_bt(const unsigned short* __restrict__ A,
                                               const unsigned short* __restrict__ Bt,
                                               void* __restrict__ Cv,
                                               int M, int N, int K,
                                               const int* __restrict__ mask) {
    __shared__ unsigned short AsL[2][128 * 32];
    __shared__ unsigned short BsL[2][128 * 32];
    const int tid = threadIdx.x;
    const int lane = tid & 63;
    const int wid = tid >> 6;
    const int lg = lane >> 4, lr = lane & 15;
    const int wm = wid >> 1, wn = wid & 1;
    const long m0 = (long)blockIdx.y * 128, n0 = (long)blockIdx.x * 128;

    f32x4 acc[4][4] = {};

    const unsigned short* aS0 = A  + (m0 + (tid >> 2)) * K + (tid & 3) * 8;
    const unsigned short* aS1 = A  + (m0 + 64 + (tid >> 2)) * K + (tid & 3) * 8;
    const unsigned short* bS0 = Bt + (n0 + (tid >> 2)) * K + (tid & 3) * 8;
    const unsigned short* bS1 = Bt + (n0 + 64 + (tid >> 2)) * K + (tid & 3) * 8;

#define GSTAGE(bufi, k0v)                                    \
    {                                                        \
        gld_lds16(aS0 + (k0v), &AsL[bufi][wid * 512]);       \
        gld_lds16(aS1 + (k0v), &AsL[bufi][2048 + wid * 512]);\
        gld_lds16(bS0 + (k0v), &BsL[bufi][wid * 512]);       \
        gld_lds16(bS1 + (k0v), &BsL[bufi][2048 + wid * 512]);\
    }

#define GREAD(cur)                                                                    \
    {                                                                                 \
        _Pragma("unroll")                                                             \
        for (int i = 0; i < 4; i++) {                                                 \
            af[i]  = *(const u16x8*)&AsL[cur][(wm * 64 + i * 16 + lr) * 32 + lg * 8]; \
            bfr[i] = *(const u16x8*)&BsL[cur][(wn * 64 + i * 16 + lr) * 32 + lg * 8]; \
        }                                                                             \
    }

#define GMFMA                                                                  \
    {                                                                          \
        _Pragma("unroll")                                                      \
        for (int i = 0; i < 4; i++)                                            \
            _Pragma("unroll")                                                  \
            for (int j = 0; j < 4; j++)                                        \
                acc[i][j] = mfma16(af[i], bfr[j], acc[i][j]);                  \
    }

    const int nk = K >> 5;
    GSTAGE(0, 0);
    GSTAGE(1, 32);
    for (int t = 0; t < nk - 1; t++) {
        const int cur = t & 1;
        u16x8 af[4], bfr[4];
        WAIT_VM(4);
        BARRIER;
        GREAD(cur);
        WAIT_LGKM0;
        BARRIER;
        if (t < nk - 2) GSTAGE(cur, (t + 2) * 32);
        GMFMA;
    }
    {
        u16x8 af[4], bfr[4];
        WAIT_VM(0);
        BARRIER;
        GREAD((nk - 1) & 1);
        GMFMA;
    }
#undef GSTAGE
#undef GREAD
#undef GMFMA

#pragma unroll
    for (int i = 0; i < 4; i++)
#pragma unroll
        for (int j = 0; j < 4; j++)
#pragma unroll
            for (int r = 0; r < 4; r++) {
                long row = m0 + wm * 64 + i * 16 + lg * 4 + r;
                long col = n0 + wn * 64 + j * 16 + lr;
                float v = acc[i][j][r];
                if (MASKED) {
                    if (!mask[row]) v = 0.0f;
                    ((float*)Cv)[row * N + col] = v;
                } else if (WRITE_BF16) {
                    ((unsigned short*)Cv)[row * N + col] = f2bf(v);
                } else {
                    ((float*)Cv)[row * N + col] = v;
                }
            }
}

// ---------------- flash attention: LDS-free main loop, reg-staged K/V ----------------
// 1024 blocks (XCD-group swizzled), 128 threads = 2 waves, wave-decoupled KV-split.
// K/V fragments are loaded global->register directly (pure row-gathers, L2-resident
// after XCD swizzle), 2-deep static double buffer (sets A/B). No LDS, no barriers,
// no lgkm waits in the main loop. Epilogue uses a small dedicated LDS exchange.
__global__ __launch_bounds__(128) void attn_kernel(const unsigned short* __restrict__ qk,
                                                   const unsigned short* __restrict__ vT,
                                                   unsigned short* __restrict__ res) {
    const int Nseq = 2048, LD = 1024;
    const long T = 8192;
    const int id = blockIdx.x;
    const int xcd = id & 7, jj = id >> 3;
    const int g = xcd + 8 * (jj & 3);       // group = h + 8*b, 4 groups per XCD
    const int qt = jj >> 2;
    const int b = g >> 3, h = g & 7;

    const int tid = threadIdx.x;
    const int wid = tid >> 6, lane = tid & 63;
    const int qL = lane & 31, hi = lane >> 5;

    __shared__ float Ox[2 * 2080];    // [qh][32 q][65 padded]
    __shared__ float lX[128];         // [qh][wave][32 q]

    // ---- Q fragments: B-operand, lane n=q=qL, k-chunk j: d = 16j + 8hi + e ----
    const int qbase = qt * 64;
    u16x8 qf[2][4];
#pragma unroll
    for (int qh = 0; qh < 2; qh++) {
        const long qrow = (long)b * Nseq + qbase + qh * 32 + qL;
#pragma unroll
        for (int j = 0; j < 4; j++)
            qf[qh][j] = *(const u16x8*)(qk + qrow * LD + h * 64 + 16 * j + 8 * hi);
    }

    f32x16 oacc[2][2] = {};   // [qh][db]: O[q=qh*32+crow(reg,hi)][d=db*32+qL]
    float ls[2] = {0.0f, 0.0f};

    // ---- per-lane direct-load base pointers (wave's KV tiles: kv0 = 64t + 32*wid) ----
    // K frag: lane (qL,hi) reads 16B at K[kv0+qL][16j+8hi]
    const unsigned short* kpA = qk + 512 + ((long)b * Nseq + 32 * wid + qL) * LD
                                + h * 64 + 8 * hi;
    // V frag: lane (qL,hi) reads 16B at vT[db*32+qL][kv0 + 16jk + 8hi]
    const unsigned short* vpA0 = vT + ((long)h * 64 + qL) * T + b * Nseq + 32 * wid + 8 * hi;
    const unsigned short* vpA1 = vpA0 + 32 * T;
    const unsigned short* kpB  = kpA + 64L * LD;     // B set starts at tile t=1
    const unsigned short* vpB0 = vpA0 + 64;
    const unsigned short* vpB1 = vpA1 + 64;

    u16x8 kfA[4], vfA[2][2], kfB[4], vfB[2][2];

#define ISSUE(S)                                                        \
    {                                                                   \
        _Pragma("unroll")                                               \
        for (int j = 0; j < 4; j++)                                     \
            kf##S[j] = *(const u16x8*)(kp##S + 16 * j);                 \
        _Pragma("unroll")                                               \
        for (int jk = 0; jk < 2; jk++) {                                \
            vf##S[0][jk] = *(const u16x8*)(vp##S##0 + 16 * jk);         \
            vf##S[1][jk] = *(const u16x8*)(vp##S##1 + 16 * jk);         \
        }                                                               \
        kp##S += 128L * LD; vp##S##0 += 128; vp##S##1 += 128;           \
    }

#define BODY(S)                                                                        \
    {                                                                                  \
        _Pragma("unroll")                                                              \
        for (int qh = 0; qh < 2; qh++) {                                               \
            f32x16 s = {};                                                             \
            __builtin_amdgcn_s_setprio(1);                                             \
            _Pragma("unroll")                                                          \
            for (int j = 0; j < 4; j++) s = mfma32(kf##S[j], qf[qh][j], s);            \
            __builtin_amdgcn_s_setprio(0);                                             \
            unsigned int w[8];                                                         \
            float lq = 0.0f;                                                           \
            _Pragma("unroll")                                                          \
            for (int i = 0; i < 8; i++) {                                              \
                float e0 = fexp2(s[2 * i]), e1 = fexp2(s[2 * i + 1]);                  \
                lq += e0 + e1;                                                         \
                w[i] = pkbf(e0, e1);                                                   \
            }                                                                          \
            ls[qh] += lq;                                                              \
            u16x8 pa[2];                                                               \
            _Pragma("unroll")                                                          \
            for (int hh = 0; hh < 2; hh++) {                                           \
                i32x2 ra = permswap(w[4 * hh + 0], w[4 * hh + 2], hi);                 \
                i32x2 rb = permswap(w[4 * hh + 1], w[4 * hh + 3], hi);                 \
                u32x4 fw;                                                              \
                fw[0] = (unsigned)ra[0]; fw[1] = (unsigned)rb[0];                      \
                fw[2] = (unsigned)ra[1]; fw[3] = (unsigned)rb[1];                      \
                pa[hh] = __builtin_bit_cast(u16x8, fw);                                \
            }                                                                          \
            __builtin_amdgcn_s_setprio(1);                                             \
            _Pragma("unroll")                                                          \
            for (int db = 0; db < 2; db++)                                             \
                _Pragma("unroll")                                                      \
                for (int jk = 0; jk < 2; jk++)                                         \
                    oacc[qh][db] = mfma32(pa[jk], vf##S[db][jk], oacc[qh][db]);        \
            __builtin_amdgcn_s_setprio(0);                                             \
        }                                                                              \
    }

    ISSUE(A);    // tile 0
    ISSUE(B);    // tile 1
    __builtin_amdgcn_sched_barrier(0);
    for (int tt = 0; tt < 15; tt++) {
        BODY(A);              // compiler emits vmcnt(8): waits A set, B stays in flight
        ISSUE(A);             // tile 2tt+2 into freed A regs
        __builtin_amdgcn_sched_barrier(0);
        BODY(B);
        ISSUE(B);             // tile 2tt+3
        __builtin_amdgcn_sched_barrier(0);
    }
    BODY(A);     // tile 30
    BODY(B);     // tile 31
#undef ISSUE
#undef BODY

    // ---- epilogue: combine partner's partial O/l (no-max softmax is linear) ----
    float lp[2];
#pragma unroll
    for (int qh = 0; qh < 2; qh++) lp[qh] = ls[qh] + __shfl_xor(ls[qh], 32);

#define EXPORT(OQ)                                                            \
    {                                                                         \
        _Pragma("unroll")                                                     \
        for (int reg = 0; reg < 16; reg++) {                                  \
            const int crow = (reg & 3) + 8 * (reg >> 2) + 4 * hi;             \
            _Pragma("unroll")                                                 \
            for (int db = 0; db < 2; db++)                                    \
                Ox[(OQ) * 2080 + crow * 65 + db * 32 + qL] = oacc[OQ][db][reg]; \
        }                                                                     \
    }
#define FINAL(MQ)                                                             \
    {                                                                         \
        _Pragma("unroll")                                                     \
        for (int reg = 0; reg < 16; reg++) {                                  \
            const int crow = (reg & 3) + 8 * (reg >> 2) + 4 * hi;             \
            float lt = lX[((MQ) * 2 + 0) * 32 + crow] + lX[((MQ) * 2 + 1) * 32 + crow]; \
            float linv = 1.0f / lt;                                           \
            long row = (long)b * Nseq + qbase + (MQ) * 32 + crow;             \
            _Pragma("unroll")                                                 \
            for (int db = 0; db < 2; db++) {                                  \
                float o = oacc[MQ][db][reg] + Ox[(MQ) * 2080 + crow * 65 + db * 32 + qL]; \
                res[row * 512 + h * 64 + db * 32 + qL] = f2bf(o * linv);      \
            }                                                                 \
        }                                                                     \
    }

    if (wid == 0) { EXPORT(1); } else { EXPORT(0); }
    if (lane < 32) {
        lX[(0 * 2 + wid) * 32 + qL] = lp[0];
        lX[(1 * 2 + wid) * 32 + qL] = lp[1];
    }
    __syncthreads();
    if (wid == 0) { FINAL(0); } else { FINAL(1); }
#undef EXPORT
#undef FINAL
}

extern "C" void kernel_launch(void* const* d_in, const int* in_sizes, int n_in,
                              void* d_out, int out_size, void* d_ws, size_t ws_size,
                              hipStream_t stream) {
    const float* x   = (const float*)d_in[0];
    const int* mask  = (const int*)d_in[1];
    const float* Wq  = (const float*)d_in[2];
    const float* Wkv = (const float*)d_in[3];
    const float* Wo  = (const float*)d_in[4];
    float* out = (float*)d_out;

    const int Nseq = 2048, D = 512;
    const long T = 8192;
    const float QSCALE = 0.125f * 1.4426950408889634f;  // d^-0.5 * log2(e)

    unsigned short* ws    = (unsigned short*)d_ws;
    unsigned short* xb    = ws;                          // T*512
    unsigned short* WqkvT = xb    + T * D;               // 1536*512
    unsigned short* WoT   = WqkvT + 1536L * 512;         // 512*512
    unsigned short* qkb   = WoT   + 512L * 512;          // T*1024
    unsigned short* vTb   = qkb   + T * 1024;            // 512*T
    unsigned short* resb  = vTb   + 512L * T;            // T*512

    cvt_f32_bf16<<<(int)(T * D / 1024), 256, 0, stream>>>(x, xb, T * D);
    transpose_cvt_tiled<<<dim3(8, 8),  256, 0, stream>>>(Wq,  WqkvT,              D, 512,  QSCALE);
    transpose_cvt_tiled<<<dim3(16, 8), 256, 0, stream>>>(Wkv, WqkvT + 512L * 512, D, 1024, 1.0f);
    transpose_cvt_tiled<<<dim3(8, 8),  256, 0, stream>>>(Wo,  WoT,                D, 512,  1.0f);

    // qk = x @ [Wq*a | Wk]   (M=T, N=1024, K=512)
    gemm_bt<1, 0><<<dim3(8, 64), 256, 0, stream>>>(xb, WqkvT, qkb, T, 1024, D, nullptr);
    // vT = Wv^T x^T          (M=512, N=T, K=512)
    gemm_bt<1, 0><<<dim3(64, 4), 256, 0, stream>>>(WqkvT + 1024L * 512, xb, vTb, D, T, D, nullptr);

    attn_kernel<<<1024, 128, 0, stream>>>(qkb, vTb, resb);

    // out = mask ? res @ Wo : 0
    gemm_bt<0, 1><<<dim3(4, 64), 256, 0, stream>>>(resb, WoT, out, T, D, D, mask);
}

// Round 14
// 105.723 us; speedup vs baseline: 1.1726x; 1.1726x over previous
//
#include <hip/hip_runtime.h>

typedef __bf16 bf16x8 __attribute__((ext_vector_type(8)));
typedef float f32x4 __attribute__((ext_vector_type(4)));
typedef float f32x16 __attribute__((ext_vector_type(16)));
typedef unsigned short u16x8 __attribute__((ext_vector_type(8)));
typedef unsigned int u32x4 __attribute__((ext_vector_type(4)));
typedef int i32x2 __attribute__((ext_vector_type(2)));

__device__ inline unsigned short f2bf(float f) {
    __bf16 h = (__bf16)f;
    return __builtin_bit_cast(unsigned short, h);
}

__device__ inline unsigned int pkbf(float lo, float hi) {
    return (unsigned int)f2bf(lo) | ((unsigned int)f2bf(hi) << 16);
}

__device__ inline float fexp2(float x) {
#if __has_builtin(__builtin_amdgcn_exp2f)
    return __builtin_amdgcn_exp2f(x);
#else
    return exp2f(x);
#endif
}

__device__ inline f32x4 mfma16(u16x8 a, u16x8 b, f32x4 c) {
    return __builtin_amdgcn_mfma_f32_16x16x32_bf16(
        __builtin_bit_cast(bf16x8, a), __builtin_bit_cast(bf16x8, b), c, 0, 0, 0);
}

__device__ inline f32x16 mfma32(u16x8 a, u16x8 b, f32x16 c) {
    return __builtin_amdgcn_mfma_f32_32x32x16_bf16(
        __builtin_bit_cast(bf16x8, a), __builtin_bit_cast(bf16x8, b), c, 0, 0, 0);
}

__device__ inline i32x2 permswap(unsigned int a, unsigned int b, int hi) {
#if __has_builtin(__builtin_amdgcn_permlane32_swap)
    (void)hi;
    return __builtin_amdgcn_permlane32_swap((int)a, (int)b, false, false);
#else
    int pa_ = __shfl_xor((int)a, 32);
    int pb_ = __shfl_xor((int)b, 32);
    i32x2 r;
    r[0] = hi ? pb_ : (int)a;
    r[1] = hi ? (int)b : pa_;
    return r;
#endif
}

__device__ inline void gld_lds16(const unsigned short* gsrc, unsigned short* ldst) {
    __builtin_amdgcn_global_load_lds(
        (const __attribute__((address_space(1))) unsigned int*)gsrc,
        (__attribute__((address_space(3))) unsigned int*)ldst, 16, 0, 0);
}

#define WAIT_VM(n)                                          \
    asm volatile("s_waitcnt vmcnt(" #n ")" ::: "memory");   \
    __builtin_amdgcn_sched_barrier(0)
#define WAIT_LGKM0                                          \
    asm volatile("s_waitcnt lgkmcnt(0)" ::: "memory");      \
    __builtin_amdgcn_sched_barrier(0)
#define BARRIER                                             \
    __builtin_amdgcn_s_barrier();                           \
    __builtin_amdgcn_sched_barrier(0)

// ---------------- elementwise f32 -> bf16 ----------------
__global__ __launch_bounds__(256) void cvt_f32_bf16(const float* __restrict__ in,
                                                    unsigned short* __restrict__ out, long n) {
    long i = ((long)blockIdx.x * blockDim.x + threadIdx.x) * 4;
    if (i >= n) return;
    float4 v = *(const float4*)(in + i);
    ushort4 r;
    r.x = f2bf(v.x); r.y = f2bf(v.y); r.z = f2bf(v.z); r.w = f2bf(v.w);
    *(ushort4*)(out + i) = r;
}

// ---------------- tiled transpose: W (K,N) f32 -> Wt (N,K) bf16, * scale ----------------
__global__ __launch_bounds__(256) void transpose_cvt_tiled(const float* __restrict__ W,
                                                           unsigned short* __restrict__ Wt,
                                                           int K, int N, float scale) {
    __shared__ float tile[64][65];
    const int n0 = blockIdx.x * 64, k0 = blockIdx.y * 64;
    const int c = threadIdx.x & 63;
    const int r4 = threadIdx.x >> 6;
#pragma unroll
    for (int i = 0; i < 16; i++) {
        int r = r4 * 16 + i;
        tile[r][c] = W[(long)(k0 + r) * N + n0 + c];
    }
    __syncthreads();
#pragma unroll
    for (int i = 0; i < 16; i++) {
        int rr = r4 * 16 + i;
        Wt[(long)(n0 + rr) * K + k0 + c] = f2bf(tile[c][rr] * scale);
    }
}

// ---------------- GEMM: C[m][n] = sum_k A[m][k] * Bt[n][k] ----------------
// 128x128 tile, BK=32, 4 waves, dbuf LDS, counted-vmcnt 2-barrier pipeline.
template<int WRITE_BF16, int MASKED>
__global__ __launch_bounds__(256) void gemm_bt(const unsigned short* __restrict__ A,
                                               const unsigned short* __restrict__ Bt,
                                               void* __restrict__ Cv,
                                               int M, int N, int K,
                                               const int* __restrict__ mask) {
    __shared__ unsigned short AsL[2][128 * 32];
    __shared__ unsigned short BsL[2][128 * 32];
    const int tid = threadIdx.x;
    const int lane = tid & 63;
    const int wid = tid >> 6;
    const int lg = lane >> 4, lr = lane & 15;
    const int wm = wid >> 1, wn = wid & 1;
    const long m0 = (long)blockIdx.y * 128, n0 = (long)blockIdx.x * 128;

    f32x4 acc[4][4] = {};

    const unsigned short* aS0 = A  + (m0 + (tid >> 2)) * K + (tid & 3) * 8;
    const unsigned short* aS1 = A  + (m0 + 64 + (tid >> 2)) * K + (tid & 3) * 8;
    const unsigned short* bS0 = Bt + (n0 + (tid >> 2)) * K + (tid & 3) * 8;
    const unsigned short* bS1 = Bt + (n0 + 64 + (tid >> 2)) * K + (tid & 3) * 8;

#define GSTAGE(bufi, k0v)                                    \
    {                                                        \
        gld_lds16(aS0 + (k0v), &AsL[bufi][wid * 512]);       \
        gld_lds16(aS1 + (k0v), &AsL[bufi][2048 + wid * 512]);\
        gld_lds16(bS0 + (k0v), &BsL[bufi][wid * 512]);       \
        gld_lds16(bS1 + (k0v), &BsL[bufi][2048 + wid * 512]);\
    }

#define GREAD(cur)                                                                    \
    {                                                                                 \
        _Pragma("unroll")                                                             \
        for (int i = 0; i < 4; i++) {                                                 \
            af[i]  = *(const u16x8*)&AsL[cur][(wm * 64 + i * 16 + lr) * 32 + lg * 8]; \
            bfr[i] = *(const u16x8*)&BsL[cur][(wn * 64 + i * 16 + lr) * 32 + lg * 8]; \
        }                                                                             \
    }

#define GMFMA                                                                  \
    {                                                                          \
        _Pragma("unroll")                                                      \
        for (int i = 0; i < 4; i++)                                            \
            _Pragma("unroll")                                                  \
            for (int j = 0; j < 4; j++)                                        \
                acc[i][j] = mfma16(af[i], bfr[j], acc[i][j]);                  \
    }

    const int nk = K >> 5;
    GSTAGE(0, 0);
    GSTAGE(1, 32);
    for (int t = 0; t < nk - 1; t++) {
        const int cur = t & 1;
        u16x8 af[4], bfr[4];
        WAIT_VM(4);
        BARRIER;
        GREAD(cur);
        WAIT_LGKM0;
        BARRIER;
        if (t < nk - 2) GSTAGE(cur, (t + 2) * 32);
        GMFMA;
    }
    {
        u16x8 af[4], bfr[4];
        WAIT_VM(0);
        BARRIER;
        GREAD((nk - 1) & 1);
        GMFMA;
    }
#undef GSTAGE
#undef GREAD
#undef GMFMA

#pragma unroll
    for (int i = 0; i < 4; i++)
#pragma unroll
        for (int j = 0; j < 4; j++)
#pragma unroll
            for (int r = 0; r < 4; r++) {
                long row = m0 + wm * 64 + i * 16 + lg * 4 + r;
                long col = n0 + wn * 64 + j * 16 + lr;
                float v = acc[i][j][r];
                if (MASKED) {
                    if (!mask[row]) v = 0.0f;
                    ((float*)Cv)[row * N + col] = v;
                } else if (WRITE_BF16) {
                    ((unsigned short*)Cv)[row * N + col] = f2bf(v);
                } else {
                    ((float*)Cv)[row * N + col] = v;
                }
            }
}

// ---------------- flash attention: 2-tile software pipeline (T15) ----------------
// grid 512 (XCD-group swizzled), 256 threads = 4 waves; wave owns 32 DISTINCT q-rows
// and iterates ALL 32 KV tiles (KVBLK=64). K/V staged cooperatively (each wave 2K+2V
// DMA loads per tile). Per body: QK^T(t+1) MFMAs interleave with exp2/pack/PV(t) —
// independent streams fill each other's stalls. Row-sum l via mfma(pa, ones) lands in
// crow layout -> epilogue is pure in-register normalize (no LDS exchange).
__global__ __launch_bounds__(256) void attn_kernel(const unsigned short* __restrict__ qk,
                                                   const unsigned short* __restrict__ vT,
                                                   unsigned short* __restrict__ res) {
    const int Nseq = 2048, LD = 1024;
    const long T = 8192;
    const int id = blockIdx.x;
    const int xcd = id & 7, jj = id >> 3;      // jj 0..63
    const int g = xcd + 8 * (jj & 3);          // group = h + 8*b, 4 groups per XCD
    const int qt = jj >> 2;                    // 0..15 (128-q tiles)
    const int b = g >> 3, h = g & 7;

    const int tid = threadIdx.x;
    const int wid = tid >> 6, lane = tid & 63;
    const int qL = lane & 31, hi = lane >> 5;

    __shared__ unsigned short KsL[2][4096];   // [buf][64 kv][64 d] granule-swizzled
    __shared__ unsigned short VsL[2][4096];   // [buf][64 d][64 kv] granule-swizzled

    // ---- Q fragments: B-operand, lane n=q=qL, chunk j: d = 16j + 8hi + e ----
    const int qbase = qt * 128 + wid * 32;
    const long qrow = (long)b * Nseq + qbase + qL;
    u16x8 qf[4];
#pragma unroll
    for (int j = 0; j < 4; j++)
        qf[j] = *(const u16x8*)(qk + qrow * LD + h * 64 + 16 * j + 8 * hi);

    f32x16 oacc[2] = {};     // [db]: O[q=crow(reg,hi)][d=db*32+qL]
    f32x16 lacc = {};        // l[q=crow(reg,hi)] (all cols equal)
    u16x8 onesf;
#pragma unroll
    for (int e = 0; e < 8; e++) onesf[e] = 0x3F80;  // bf16 1.0

    // ---- staging sources: wave stages granule-groups 2*wid, 2*wid+1 ----
    const int Rsub = lane >> 3, psw = ((lane & 7) ^ (Rsub & 7)) * 8;
    const int R0 = 16 * wid + Rsub;            // rows for group 0; +8 for group 1
    const unsigned short* kS = qk + 512 + ((long)b * Nseq + R0) * LD + h * 64 + psw;
    const unsigned short* vS = vT + ((long)h * 64 + R0) * T + (long)b * Nseq + psw;
    const int rsw = qL & 7;

#define STAGE(bufi)                                                            \
    {                                                                          \
        gld_lds16(kS,             &KsL[bufi][(2 * wid + 0) * 512]);            \
        gld_lds16(kS + 8L * LD,   &KsL[bufi][(2 * wid + 1) * 512]);            \
        gld_lds16(vS,             &VsL[bufi][(2 * wid + 0) * 512]);            \
        gld_lds16(vS + 8L * T,    &VsL[bufi][(2 * wid + 1) * 512]);            \
        kS += 64L * LD; vS += 64;                                              \
    }

#define READ_KF(buf)                                                           \
    {                                                                          \
        _Pragma("unroll")                                                      \
        for (int kvb = 0; kvb < 2; kvb++)                                      \
            _Pragma("unroll")                                                  \
            for (int j = 0; j < 4; j++)                                        \
                kf[kvb][j] = *(const u16x8*)&KsL[buf][(kvb * 32 + qL) * 64     \
                                                      + ((2 * j + hi) ^ rsw) * 8]; \
    }
#define READ_VF(buf)                                                           \
    {                                                                          \
        _Pragma("unroll")                                                      \
        for (int db = 0; db < 2; db++)                                         \
            _Pragma("unroll")                                                  \
            for (int jk = 0; jk < 4; jk++)                                     \
                vf[db][jk] = *(const u16x8*)&VsL[buf][(db * 32 + qL) * 64      \
                                                      + ((2 * jk + hi) ^ rsw) * 8]; \
    }

#define PACK_PV(SC)                                                                    \
    {                                                                                  \
        u16x8 pa[4];                                                                   \
        _Pragma("unroll")                                                              \
        for (int kvb = 0; kvb < 2; kvb++) {                                            \
            unsigned int w[8];                                                         \
            _Pragma("unroll")                                                          \
            for (int i = 0; i < 8; i++)                                                \
                w[i] = pkbf(fexp2(SC[kvb][2 * i]), fexp2(SC[kvb][2 * i + 1]));         \
            _Pragma("unroll")                                                          \
            for (int hh = 0; hh < 2; hh++) {                                           \
                i32x2 ra = permswap(w[4 * hh + 0], w[4 * hh + 2], hi);                 \
                i32x2 rb = permswap(w[4 * hh + 1], w[4 * hh + 3], hi);                 \
                u32x4 fw;                                                              \
                fw[0] = (unsigned)ra[0]; fw[1] = (unsigned)rb[0];                      \
                fw[2] = (unsigned)ra[1]; fw[3] = (unsigned)rb[1];                      \
                pa[kvb * 2 + hh] = __builtin_bit_cast(u16x8, fw);                      \
            }                                                                          \
        }                                                                              \
        _Pragma("unroll")                                                              \
        for (int jk = 0; jk < 4; jk++) {                                               \
            lacc = mfma32(pa[jk], onesf, lacc);                                        \
            oacc[0] = mfma32(pa[jk], vf[0][jk], oacc[0]);                              \
            oacc[1] = mfma32(pa[jk], vf[1][jk], oacc[1]);                              \
        }                                                                              \
    }

#define QKNEXT(SN)                                                                     \
    {                                                                                  \
        SN[0] = (f32x16){}; SN[1] = (f32x16){};                                        \
        _Pragma("unroll")                                                              \
        for (int j = 0; j < 4; j++) {                                                  \
            SN[0] = mfma32(kf[0][j], qf[j], SN[0]);                                    \
            SN[1] = mfma32(kf[1][j], qf[j], SN[1]);                                    \
        }                                                                              \
    }

#define STEP(SC, SN, rdbufK, rdbufV, doStage, stagebuf)                                \
    {                                                                                  \
        WAIT_VM(2);                                                                    \
        BARRIER;                                                                       \
        READ_KF(rdbufK);                                                               \
        READ_VF(rdbufV);                                                               \
        WAIT_LGKM0;                                                                    \
        BARRIER;                                                                       \
        if (doStage) STAGE(stagebuf);                                                  \
        QKNEXT(SN);                                                                    \
        PACK_PV(SC);                                                                   \
    }

    u16x8 kf[2][4], vf[2][4];
    f32x16 sA2[2], sB2[2];

    // ---- prologue: stage tiles 0,1; compute sA2 = QK(0) ----
    STAGE(0);            // tile 0  (2K + 2V loads per wave)
    STAGE(1);            // tile 1
    WAIT_VM(6);          // tile-0 K halves landed (own queue: 2 of 8 drained)
    BARRIER;             // all waves' tile-0 K landed
    READ_KF(0);
    WAIT_LGKM0;
    QKNEXT(sA2);         // scores of tile 0

    // ---- main loop: tiles 0..29 consumed; QK(t+1) overlaps PV(t) ----
    for (int t = 0; t < 30; t += 2) {
        STEP(sA2, sB2, 1, 0, 1, 0);   // consume t:   kf(t+1)<-buf1, vf(t)<-buf0, stage t+2->buf0
        STEP(sB2, sA2, 0, 1, 1, 1);   // consume t+1: kf(t+2)<-buf0, vf(t+1)<-buf1, stage t+3->buf1
    }
    {   // t = 30: consume sA2, produce sB2 (tile 31 scores), no stage
        WAIT_VM(2);
        BARRIER;
        READ_KF(1);
        READ_VF(0);
        WAIT_LGKM0;
        QKNEXT(sB2);
        PACK_PV(sA2);
    }
    {   // t = 31: PV only
        WAIT_VM(0);
        BARRIER;
        READ_VF(1);
        WAIT_LGKM0;
        PACK_PV(sB2);
    }
#undef STAGE
#undef READ_KF
#undef READ_VF
#undef PACK_PV
#undef QKNEXT
#undef STEP

    // ---- epilogue: pure in-register normalize (l is in crow layout via mfma-ones) ----
#pragma unroll
    for (int reg = 0; reg < 16; reg++) {
        const int crow = (reg & 3) + 8 * (reg >> 2) + 4 * hi;
        float linv = 1.0f / lacc[reg];
        long row = (long)b * Nseq + qbase + crow;
        res[row * 512 + h * 64 + qL]      = f2bf(oacc[0][reg] * linv);
        res[row * 512 + h * 64 + 32 + qL] = f2bf(oacc[1][reg] * linv);
    }
}

extern "C" void kernel_launch(void* const* d_in, const int* in_sizes, int n_in,
                              void* d_out, int out_size, void* d_ws, size_t ws_size,
                              hipStream_t stream) {
    const float* x   = (const float*)d_in[0];
    const int* mask  = (const int*)d_in[1];
    const float* Wq  = (const float*)d_in[2];
    const float* Wkv = (const float*)d_in[3];
    const float* Wo  = (const float*)d_in[4];
    float* out = (float*)d_out;

    const int Nseq = 2048, D = 512;
    const long T = 8192;
    const float QSCALE = 0.125f * 1.4426950408889634f;  // d^-0.5 * log2(e)

    unsigned short* ws    = (unsigned short*)d_ws;
    unsigned short* xb    = ws;                          // T*512
    unsigned short* WqkvT = xb    + T * D;               // 1536*512
    unsigned short* WoT   = WqkvT + 1536L * 512;         // 512*512
    unsigned short* qkb   = WoT   + 512L * 512;          // T*1024
    unsigned short* vTb   = qkb   + T * 1024;            // 512*T
    unsigned short* resb  = vTb   + 512L * T;            // T*512

    cvt_f32_bf16<<<(int)(T * D / 1024), 256, 0, stream>>>(x, xb, T * D);
    transpose_cvt_tiled<<<dim3(8, 8),  256, 0, stream>>>(Wq,  WqkvT,              D, 512,  QSCALE);
    transpose_cvt_tiled<<<dim3(16, 8), 256, 0, stream>>>(Wkv, WqkvT + 512L * 512, D, 1024, 1.0f);
    transpose_cvt_tiled<<<dim3(8, 8),  256, 0, stream>>>(Wo,  WoT,                D, 512,  1.0f);

    // qk = x @ [Wq*a | Wk]   (M=T, N=1024, K=512)
    gemm_bt<1, 0><<<dim3(8, 64), 256, 0, stream>>>(xb, WqkvT, qkb, T, 1024, D, nullptr);
    // vT = Wv^T x^T          (M=512, N=T, K=512)
    gemm_bt<1, 0><<<dim3(64, 4), 256, 0, stream>>>(WqkvT + 1024L * 512, xb, vTb, D, T, D, nullptr);

    attn_kernel<<<512, 256, 0, stream>>>(qkb, vTb, resb);

    // out = mask ? res @ Wo : 0
    gemm_bt<0, 1><<<dim3(4, 64), 256, 0, stream>>>(resb, WoT, out, T, D, D, mask);
}